// Round 12
// baseline (4011.723 us; speedup 1.0000x reference)
//
#include <hip/hip_runtime.h>
#include <hip/hip_bf16.h>

// RL2 LSTM fused kernel, round 12.
// After 5 failed redesigns of the cross-block h-exchange (r5,6,7,9,11) and a
// proven 6.4us/step MALL-latency floor on the working form (r4/r8/r10), r12
// ELIMINATES inter-block communication entirely:
//   k_lstm: 32 blocks x 16 batch rows; each block computes ALL 1024 gate
//   outputs for its rows. Full pc-permuted W2=[Wx;Wh]^T (1024x512 bf16, 1MB)
//   streams from L2 as MFMA A-fragments (read-only, no coherence). h lives in
//   a block-local LDS double buffer. 1024 MFMAs/step/block ~ 2.1us, 128 steps.
//   No tags, no sc bits, no spins -- cannot hang, no dispatch assumptions.
// h_seq[t] is written into the consumed x slot t (same block, same rows, no
// cross-block interaction); k_head computes logits/values (no atomics).
// k_prep drops swizzle/hdb/bias-prefill; k_x unchanged.

#define WS_TT   0u
#define WS_CT   409600u
#define WS_AT   819200u
#define WS_WD1  825344u
#define WS_B1T  829440u
#define WS_WRW  830464u
#define WS_WDN  831488u
#define WS_W2T  1048576u   // 1024 pc x 512 k bf16 (plain layout): 1MB
#define WS_X    4194304u   // 128 slots x 512 x 256 u16 = 32MB (r4 footprint)

typedef __attribute__((ext_vector_type(8))) short s8v;
typedef __attribute__((ext_vector_type(4))) float f4v;
typedef __attribute__((ext_vector_type(4))) unsigned u4v;
typedef unsigned short u16;
typedef unsigned char u8;

union U4 { u4v v4; unsigned u[4]; };

__device__ __forceinline__ float sigm_(float x) {
  return __builtin_amdgcn_rcpf(1.f + __expf(-x));
}
__device__ __forceinline__ float tanh_(float x) {
  return 1.f - 2.f * __builtin_amdgcn_rcpf(1.f + __expf(2.f * x));
}

// ---------------- fused prep: tables + W2 ----------------------------------
__global__ __launch_bounds__(256) void k_prep(
    const float* tile_emb, const float* color_emb, const float* action_emb,
    const float* Wdir, const float* bdir, const float* W1, const float* b1,
    const float* Wx, const float* Wh, char* ws) {
  int id = blockIdx.x;
  int h = threadIdx.x;
  if (id < 816) {
    // ---- encoder tables ----
    float* TT  = (float*)(ws + WS_TT);
    float* CT  = (float*)(ws + WS_CT);
    float* AT  = (float*)(ws + WS_AT);
    float* WD1 = (float*)(ws + WS_WD1);
    float* B1T = (float*)(ws + WS_B1T);
    float* WRW = (float*)(ws + WS_WRW);
    float* WDN = (float*)(ws + WS_WDN);
    if (id < 400) {                 // Ttab[p][v][h]
      int p = id >> 4, v = id & 15;
      float s = 0.f;
#pragma unroll
      for (int e = 0; e < 16; ++e) s += tile_emb[v * 16 + e] * W1[(p * 32 + e) * 256 + h];
      TT[id * 256 + h] = s;
    } else if (id < 800) {          // Ctab[p][v][h]
      int p = (id - 400) >> 4, v = id & 15;
      float s = 0.f;
#pragma unroll
      for (int e = 0; e < 16; ++e) s += color_emb[v * 16 + e] * W1[(p * 32 + 16 + e) * 256 + h];
      CT[(id - 400) * 256 + h] = s;
    } else {
      int r = id - 800;
      if (r < 6) {
        float s = 0.f;
#pragma unroll
        for (int e = 0; e < 16; ++e) s += action_emb[r * 16 + e] * W1[(816 + e) * 256 + h];
        AT[r * 256 + h] = s;
      } else if (r < 10) {
        int d = r - 6;
        float s = 0.f;
#pragma unroll
        for (int e = 0; e < 16; ++e) s += Wdir[d * 16 + e] * W1[(800 + e) * 256 + h];
        WD1[d * 256 + h] = s;
      } else if (r == 10) {
        float s = b1[h];
#pragma unroll
        for (int e = 0; e < 16; ++e) s += bdir[e] * W1[(800 + e) * 256 + h];
        B1T[h] = s;
      } else if (r == 11) {
        WRW[h] = W1[832 * 256 + h];
      } else if (r == 12) {
        WDN[h] = W1[833 * 256 + h];
      }
    }
  } else {
    // ---- W2 = [Wx;Wh]^T bf16, pc-permuted, PLAIN row-major [pc][512 k] ----
    // pc = (j>>2)*16 + (j&3)*4 + gate  for orig col n = gate*256 + j.
    int wb = id - 816;                 // 0..127, covers k = wb*4 .. wb*4+3
    u16* W2 = (u16*)(ws + WS_W2T);
#pragma unroll
    for (int kk = 0; kk < 4; ++kk) {
      int k = wb * 4 + kk;
      const float* row = (k < 256) ? (Wx + (size_t)k * 1024)
                                   : (Wh + (size_t)(k - 256) * 1024);
      float4 v4 = *(const float4*)(row + h * 4);
      float vv[4] = {v4.x, v4.y, v4.z, v4.w};
#pragma unroll
      for (int e = 0; e < 4; ++e) {
        int n = h * 4 + e;
        int g = n >> 8, j = n & 255;
        int pc = (j >> 2) * 16 + (j & 3) * 4 + g;
        __hip_bfloat16 bv16 = __float2bfloat16(vv[e]);
        W2[(size_t)pc * 512 + k] = *(u16*)&bv16;
      }
    }
  }
}

// ---------------- x = relu(enc @ W1 + b1)  via tables -----------------------
__global__ __launch_bounds__(512, 1) void k_x(
    const int* obs_img, const float* obs_dir, const int* prev_action,
    const float* prev_reward, const float* done, char* ws) {
  __shared__ float TtL[12800];   // [25*16][32]
  __shared__ float CtL[12800];
  __shared__ float AtL[192];
  __shared__ float WdL[128];
  __shared__ u8 pkT[6400];       // [256 tb][25]
  __shared__ u8 pkC[6400];
  __shared__ u8 actL[256];
  __shared__ float rewL[256];
  __shared__ float dnL[256];
  __shared__ float dirL[1024];

  const float* TT  = (const float*)(ws + WS_TT);
  const float* CT  = (const float*)(ws + WS_CT);
  const float* AT  = (const float*)(ws + WS_AT);
  const float* WD1 = (const float*)(ws + WS_WD1);
  const float* B1T = (const float*)(ws + WS_B1T);
  const float* WRW = (const float*)(ws + WS_WRW);
  const float* WDN = (const float*)(ws + WS_WDN);
  __hip_bfloat16* xout = (__hip_bfloat16*)(ws + WS_X);

  int bid = blockIdx.x;          // 512 blocks
  int slice = bid & 7, grp = bid >> 3;   // 64 groups x 1024 tb
  int h0 = slice * 32;
  int tid = threadIdx.x;
  int sub = tid >> 5, hh = tid & 31;

  for (int e = tid; e < 12800; e += 512) {
    int pv = e >> 5, k = e & 31;
    TtL[e] = TT[pv * 256 + h0 + k];
    CtL[e] = CT[pv * 256 + h0 + k];
  }
  for (int e = tid; e < 192; e += 512) AtL[e] = AT[(e >> 5) * 256 + h0 + (e & 31)];
  for (int e = tid; e < 128; e += 512) WdL[e] = WD1[(e >> 5) * 256 + h0 + (e & 31)];
  float b1r = B1T[h0 + hh], wrr = WRW[h0 + hh], wdr = WDN[h0 + hh];

  for (int cg = 0; cg < 4; ++cg) {
    int tb0 = grp * 1024 + cg * 256;
    __syncthreads();
    for (int e = tid; e < 6400; e += 512) {
      int tbl = e / 25, p = e - tbl * 25;
      int base = ((tb0 + tbl) * 25 + p) * 2;
      pkT[e] = (u8)obs_img[base];
      pkC[e] = (u8)obs_img[base + 1];
    }
    for (int e = tid; e < 256; e += 512) {
      actL[e] = (u8)prev_action[tb0 + e];
      rewL[e] = prev_reward[tb0 + e];
      dnL[e]  = done[tb0 + e];
    }
    for (int e = tid; e < 1024; e += 512) dirL[e] = obs_dir[(size_t)tb0 * 4 + e];
    __syncthreads();

    for (int pass = 0; pass < 16; ++pass) {
      int tbl = pass * 16 + sub;
      float s0 = b1r, s1 = 0.f;
#pragma unroll
      for (int p = 0; p < 25; ++p) {
        int tv = pkT[tbl * 25 + p];
        int cv = pkC[tbl * 25 + p];
        s0 += TtL[(p * 16 + tv) * 32 + hh];
        s1 += CtL[(p * 16 + cv) * 32 + hh];
      }
      s0 += AtL[(int)actL[tbl] * 32 + hh];
      float d0 = dirL[tbl * 4 + 0], d1 = dirL[tbl * 4 + 1];
      float d2 = dirL[tbl * 4 + 2], d3 = dirL[tbl * 4 + 3];
      s1 += d0 * WdL[hh] + d1 * WdL[32 + hh] + d2 * WdL[64 + hh] + d3 * WdL[96 + hh];
      s0 += rewL[tbl] * wrr + dnL[tbl] * wdr;
      float xv = fmaxf(s0 + s1, 0.f);
      xout[(size_t)(tb0 + tbl) * 256 + h0 + hh] = __float2bfloat16(xv);
    }
  }
}

// ---------------- block-local LSTM (no inter-block comms) -------------------
__global__ __launch_bounds__(512, 1) void k_lstm(
    const float* c0, const float* h0, const float* bh, float* out, char* ws) {
  __shared__ u16 hl[2][16][264];   // h double buffer, +8 pad (bank spread)

  u16* xseq = (u16*)(ws + WS_X);
  const u16* w2 = (const u16*)(ws + WS_W2T);

  const int tid = threadIdx.x;
  const int bid = blockIdx.x;      // 0..31
  const int b0 = bid * 16;
  const int lane = tid & 63, wv = tid >> 6;   // 8 waves
  const int G = lane >> 4, bl = lane & 15;

  // ---- init h state from h0 (f32 -> bf16) ----
  {
    int b = tid >> 5, j0 = (tid & 31) * 8;
#pragma unroll
    for (int e = 0; e < 8; ++e) {
      __hip_bfloat16 hb = __float2bfloat16(h0[(size_t)(b0 + b) * 256 + j0 + e]);
      hl[0][b][j0 + e] = *(u16*)&hb;
    }
  }

  // ---- per-wave A row pointers: tile i covers pc rows [ (wv*8+i)*16, +16 ) ----
  const u16* arow[8];
#pragma unroll
  for (int i = 0; i < 8; ++i)
    arow[i] = w2 + (size_t)((wv * 8 + i) * 16 + bl) * 512 + G * 8;

  // ---- biases + c state (lane owns j = wv*32 + i*4 + G, b = b0+bl) ----
  float bhv[8][4], cs[8];
#pragma unroll
  for (int i = 0; i < 8; ++i) {
    int j = wv * 32 + i * 4 + G;
#pragma unroll
    for (int r = 0; r < 4; ++r) bhv[i][r] = bh[r * 256 + j];
    cs[i] = c0[(size_t)(b0 + bl) * 256 + j];
  }
  __syncthreads();

  // ---- x prologue (slot 0) ----
  s8v xf[8];
  {
    const u16* xr = xseq + ((size_t)0 * 512 + (b0 + bl)) * 256 + 8 * G;
#pragma unroll
    for (int ks = 0; ks < 8; ++ks) xf[ks] = *(const s8v*)(xr + ks * 32);
  }

  float* out_cf = out + 458752;
  float* out_hf = out + 589824;

  for (int t = 0; t < 128; ++t) {
    const int cur = t & 1, nxt = cur ^ 1;

    // prefetch next-step x (no consumer until next iter -> overlaps MFMAs)
    s8v xfn[8];
    if (t < 127) {
      const u16* xrn = xseq + ((size_t)(t + 1) * 512 + (b0 + bl)) * 256 + 8 * G;
#pragma unroll
      for (int ks = 0; ks < 8; ++ks) xfn[ks] = *(const s8v*)(xrn + ks * 32);
    }

    // ---- MFMAs: 8 tiles x 16 k-chunks; A streamed from L2, B from regs/LDS
    f4v acc[8];
#pragma unroll
    for (int i = 0; i < 8; ++i) acc[i] = (f4v){0.f, 0.f, 0.f, 0.f};
#pragma unroll
    for (int kc = 0; kc < 16; ++kc) {
      s8v bfr;
      if (kc < 8) bfr = xf[kc];
      else bfr = *(const s8v*)&hl[cur][bl][(kc - 8) * 32 + G * 8];
#pragma unroll
      for (int i = 0; i < 8; ++i) {
        s8v a = *(const s8v*)(arow[i] + kc * 32);
        acc[i] = __builtin_amdgcn_mfma_f32_16x16x32_bf16(a, bfr, acc[i], 0, 0, 0);
      }
    }

    // ---- gates + h update (all lane-local) ----
#pragma unroll
    for (int i = 0; i < 8; ++i) {
      int j = wv * 32 + i * 4 + G;
      float zi = acc[i][0] + bhv[i][0], zf = acc[i][1] + bhv[i][1];
      float zg = acc[i][2] + bhv[i][2], zo = acc[i][3] + bhv[i][3];
      float cn = sigm_(zf) * cs[i] + sigm_(zi) * tanh_(zg);
      float hn = sigm_(zo) * tanh_(cn);
      cs[i] = cn;
      __hip_bfloat16 hb = __float2bfloat16(hn);
      hl[nxt][bl][j] = *(u16*)&hb;
      if (t == 127) {
        out_cf[(size_t)(b0 + bl) * 256 + j] = cn;
        out_hf[(size_t)(b0 + bl) * 256 + j] = hn;
      }
    }

    __syncthreads();   // hl[nxt] complete

    // ---- h_seq[t] -> slot t (coalesced; own rows only, x[t] already consumed)
    {
      int b = tid >> 5, c8 = (tid & 31) * 8;
      u4v v = *(const u4v*)&hl[nxt][b][c8];
      *(u4v*)(xseq + ((size_t)t * 512 + (b0 + b)) * 256 + c8) = v;
    }

    if (t < 127) {
#pragma unroll
      for (int ks = 0; ks < 8; ++ks) xf[ks] = xfn[ks];
    }
  }
}

// ---------------- heads: logits/values from h_seq ---------------------------
__global__ __launch_bounds__(256) void k_head(
    const float* Wpi, const float* bpi, const float* Wv, const float* bv,
    float* out, const char* ws) {
  __shared__ float WL[256][8];
  int tid = threadIdx.x;
#pragma unroll
  for (int a = 0; a < 8; ++a)
    WL[tid][a] = (a < 6) ? Wpi[tid * 6 + a] : ((a == 6) ? Wv[tid] : 0.f);
  __syncthreads();

  int row = blockIdx.x * 256 + tid;      // tb in [0, 65536)
  const u16* hr = (const u16*)(ws + WS_X) + (size_t)row * 256;
  float acc[7] = {0.f, 0.f, 0.f, 0.f, 0.f, 0.f, 0.f};
  for (int k0 = 0; k0 < 32; ++k0) {
    U4 v;
    v.v4 = *(const u4v*)(hr + k0 * 8);
#pragma unroll
    for (int e = 0; e < 8; ++e) {
      unsigned hw = (e & 1) ? (v.u[e >> 1] >> 16) : (v.u[e >> 1] & 0xffffu);
      float f = __uint_as_float(hw << 16);
      int h = k0 * 8 + e;
#pragma unroll
      for (int a = 0; a < 7; ++a) acc[a] += f * WL[h][a];
    }
  }
  float* out_logits = out;
  float* out_values = out + 393216;
#pragma unroll
  for (int a = 0; a < 6; ++a) out_logits[(size_t)row * 6 + a] = acc[a] + bpi[a];
  out_values[row] = acc[6] + bv[0];
}

extern "C" void kernel_launch(void* const* d_in, const int* in_sizes, int n_in,
                              void* d_out, int out_size, void* d_ws, size_t ws_size,
                              hipStream_t stream) {
  const int*   obs_img     = (const int*)d_in[0];
  const float* obs_dir     = (const float*)d_in[1];
  const int*   prev_action = (const int*)d_in[2];
  const float* prev_reward = (const float*)d_in[3];
  const float* done        = (const float*)d_in[4];
  const float* c0          = (const float*)d_in[5];
  const float* h0          = (const float*)d_in[6];
  const float* tile_emb    = (const float*)d_in[7];
  const float* color_emb   = (const float*)d_in[8];
  const float* action_emb  = (const float*)d_in[9];
  const float* Wdir        = (const float*)d_in[10];
  const float* bdir        = (const float*)d_in[11];
  const float* W1          = (const float*)d_in[12];
  const float* b1          = (const float*)d_in[13];
  const float* Wx          = (const float*)d_in[14];
  const float* Wh          = (const float*)d_in[15];
  const float* bh          = (const float*)d_in[16];
  const float* Wpi         = (const float*)d_in[17];
  const float* bpi         = (const float*)d_in[18];
  const float* Wv          = (const float*)d_in[19];
  const float* bv          = (const float*)d_in[20];
  (void)in_sizes; (void)n_in; (void)out_size; (void)ws_size;

  char* ws = (char*)d_ws;
  float* out = (float*)d_out;

  k_prep<<<944, 256, 0, stream>>>(tile_emb, color_emb, action_emb, Wdir, bdir,
                                  W1, b1, Wx, Wh, ws);
  k_x<<<512, 512, 0, stream>>>(obs_img, obs_dir, prev_action, prev_reward, done, ws);
  k_lstm<<<32, 512, 0, stream>>>(c0, h0, bh, out, ws);
  k_head<<<256, 256, 0, stream>>>(Wpi, bpi, Wv, bv, out, ws);
}

// Round 13
// 1294.197 us; speedup vs baseline: 3.0998x; 3.0998x over previous
//
#include <hip/hip_runtime.h>
#include <hip/hip_bf16.h>

// RL2 LSTM fused kernel, round 13.
// r12 (block-local, weight-streaming) hit the per-CU L2-BW floor (29us/step)
// -- reverted. But it flagged the untested serializer in r4/r8/r10: per-step
// atomicAdds from waves 2-3 hit the SAME 6-8 floats from all 8 cluster
// blocks (contended MALL RMW ~2-3us), drained INSIDE the next step's vmcnt.
// r13 = r10 k_lstm with the logits head excised:
//  - no WpiL / part[] / shfl-reduce / atomicAdd in the loop;
//  - wave 1 writes h_seq[t-1] (live in hstage[t&1]) into consumed x slot t-1
//    at step t (safe: tag-t detect => all 8 peers finished step-(t-1)
//    x-reads of that slot); h_seq[127] comes from out_hf (f32) in k_head.
//  - k_head (r12-proven, no atomics) computes logits/values afterwards.
// Everything else (detect, early publish, vmcnt split, backoff) = r10.

#define WS_TT   0u
#define WS_CT   409600u
#define WS_AT   819200u
#define WS_WD1  825344u
#define WS_B1T  829440u
#define WS_WRW  830464u
#define WS_WDN  831488u
#define WS_W2T  1048576u   // 1024 pc x 512 k bf16, swizzled: 1MB
#define WS_HDB  2097152u   // ring: 2 x 512 x 256 tagged dwords = 1MB
#define WS_X    4194304u   // 128 slots x 512 x 256 u16 = 32MB
                           // slot t: x[t]; h_seq[t] overwrites it at step t+1

typedef __attribute__((ext_vector_type(8))) short s8v;
typedef __attribute__((ext_vector_type(4))) float f4v;
typedef __attribute__((ext_vector_type(4))) unsigned u4v;
typedef unsigned short u16;
typedef unsigned char u8;

union U4 { u4v v4; unsigned u[4]; };

__device__ __forceinline__ float sigm_(float x) {
  return __builtin_amdgcn_rcpf(1.f + __expf(-x));
}
__device__ __forceinline__ float tanh_(float x) {
  return 1.f - 2.f * __builtin_amdgcn_rcpf(1.f + __expf(2.f * x));
}

// ---------------- fused prep: tables + W2T + h0 ring init -------------------
__global__ __launch_bounds__(256) void k_prep(
    const float* tile_emb, const float* color_emb, const float* action_emb,
    const float* Wdir, const float* bdir, const float* W1, const float* b1,
    const float* Wx, const float* Wh, const float* h0, char* ws) {
  int id = blockIdx.x;
  int h = threadIdx.x;
  if (id < 816) {
    // ---- encoder tables ----
    float* TT  = (float*)(ws + WS_TT);
    float* CT  = (float*)(ws + WS_CT);
    float* AT  = (float*)(ws + WS_AT);
    float* WD1 = (float*)(ws + WS_WD1);
    float* B1T = (float*)(ws + WS_B1T);
    float* WRW = (float*)(ws + WS_WRW);
    float* WDN = (float*)(ws + WS_WDN);
    if (id < 400) {                 // Ttab[p][v][h]
      int p = id >> 4, v = id & 15;
      float s = 0.f;
#pragma unroll
      for (int e = 0; e < 16; ++e) s += tile_emb[v * 16 + e] * W1[(p * 32 + e) * 256 + h];
      TT[id * 256 + h] = s;
    } else if (id < 800) {          // Ctab[p][v][h]
      int p = (id - 400) >> 4, v = id & 15;
      float s = 0.f;
#pragma unroll
      for (int e = 0; e < 16; ++e) s += color_emb[v * 16 + e] * W1[(p * 32 + 16 + e) * 256 + h];
      CT[(id - 400) * 256 + h] = s;
    } else {
      int r = id - 800;
      if (r < 6) {
        float s = 0.f;
#pragma unroll
        for (int e = 0; e < 16; ++e) s += action_emb[r * 16 + e] * W1[(816 + e) * 256 + h];
        AT[r * 256 + h] = s;
      } else if (r < 10) {
        int d = r - 6;
        float s = 0.f;
#pragma unroll
        for (int e = 0; e < 16; ++e) s += Wdir[d * 16 + e] * W1[(800 + e) * 256 + h];
        WD1[d * 256 + h] = s;
      } else if (r == 10) {
        float s = b1[h];
#pragma unroll
        for (int e = 0; e < 16; ++e) s += bdir[e] * W1[(800 + e) * 256 + h];
        B1T[h] = s;
      } else if (r == 11) {
        WRW[h] = W1[832 * 256 + h];
      } else if (r == 12) {
        WDN[h] = W1[833 * 256 + h];
      }
    }
  } else if (id < 944) {
    // ---- W2T = [Wx;Wh]^T bf16, pc-permuted, LDS-XOR-preswizzled ----
    int wb = id - 816;
#pragma unroll
    for (int kk = 0; kk < 4; ++kk) {
      int k = wb * 4 + kk;
      const float* row = (k < 256) ? (Wx + (size_t)k * 1024)
                                   : (Wh + (size_t)(k - 256) * 1024);
      float4 v4 = *(const float4*)(row + h * 4);
      float vv[4] = {v4.x, v4.y, v4.z, v4.w};
#pragma unroll
      for (int e = 0; e < 4; ++e) {
        int n = h * 4 + e;
        int gate = n >> 8, rem = n & 255;
        int q = rem >> 5, jl = rem & 31;
        int pcl = (jl >> 2) * 16 + (jl & 3) * 4 + gate;
        unsigned byteoff = ((unsigned)(pcl << 10) + (unsigned)(k << 1)) ^
                           (((unsigned)(pcl & 7)) << 4);
        __hip_bfloat16 bv16 = __float2bfloat16(vv[e]);
        *(u16*)(ws + WS_W2T + (size_t)q * 131072u + byteoff) = *(u16*)&bv16;
      }
    }
  } else {
    // ---- h0 -> ring slot 0, tagged 0 ----
    int i = (id - 944) * 256 + h;
    unsigned* hdb = (unsigned*)(ws + WS_HDB);
    __hip_bfloat16 hb = __float2bfloat16(h0[i]);
    hdb[i] = (unsigned)*(u16*)&hb;
  }
}

// ---------------- x = relu(enc @ W1 + b1)  via tables -----------------------
__global__ __launch_bounds__(512, 1) void k_x(
    const int* obs_img, const float* obs_dir, const int* prev_action,
    const float* prev_reward, const float* done, char* ws) {
  __shared__ float TtL[12800];   // [25*16][32]
  __shared__ float CtL[12800];
  __shared__ float AtL[192];
  __shared__ float WdL[128];
  __shared__ u8 pkT[6400];       // [256 tb][25]
  __shared__ u8 pkC[6400];
  __shared__ u8 actL[256];
  __shared__ float rewL[256];
  __shared__ float dnL[256];
  __shared__ float dirL[1024];

  const float* TT  = (const float*)(ws + WS_TT);
  const float* CT  = (const float*)(ws + WS_CT);
  const float* AT  = (const float*)(ws + WS_AT);
  const float* WD1 = (const float*)(ws + WS_WD1);
  const float* B1T = (const float*)(ws + WS_B1T);
  const float* WRW = (const float*)(ws + WS_WRW);
  const float* WDN = (const float*)(ws + WS_WDN);
  __hip_bfloat16* xout = (__hip_bfloat16*)(ws + WS_X);

  int bid = blockIdx.x;          // 512 blocks
  int slice = bid & 7, grp = bid >> 3;   // 64 groups x 1024 tb
  int h0 = slice * 32;
  int tid = threadIdx.x;
  int sub = tid >> 5, hh = tid & 31;

  for (int e = tid; e < 12800; e += 512) {
    int pv = e >> 5, k = e & 31;
    TtL[e] = TT[pv * 256 + h0 + k];
    CtL[e] = CT[pv * 256 + h0 + k];
  }
  for (int e = tid; e < 192; e += 512) AtL[e] = AT[(e >> 5) * 256 + h0 + (e & 31)];
  for (int e = tid; e < 128; e += 512) WdL[e] = WD1[(e >> 5) * 256 + h0 + (e & 31)];
  float b1r = B1T[h0 + hh], wrr = WRW[h0 + hh], wdr = WDN[h0 + hh];

  for (int cg = 0; cg < 4; ++cg) {
    int tb0 = grp * 1024 + cg * 256;
    __syncthreads();
    for (int e = tid; e < 6400; e += 512) {
      int tbl = e / 25, p = e - tbl * 25;
      int base = ((tb0 + tbl) * 25 + p) * 2;
      pkT[e] = (u8)obs_img[base];
      pkC[e] = (u8)obs_img[base + 1];
    }
    for (int e = tid; e < 256; e += 512) {
      actL[e] = (u8)prev_action[tb0 + e];
      rewL[e] = prev_reward[tb0 + e];
      dnL[e]  = done[tb0 + e];
    }
    for (int e = tid; e < 1024; e += 512) dirL[e] = obs_dir[(size_t)tb0 * 4 + e];
    __syncthreads();

    for (int pass = 0; pass < 16; ++pass) {
      int tbl = pass * 16 + sub;
      float s0 = b1r, s1 = 0.f;
#pragma unroll
      for (int p = 0; p < 25; ++p) {
        int tv = pkT[tbl * 25 + p];
        int cv = pkC[tbl * 25 + p];
        s0 += TtL[(p * 16 + tv) * 32 + hh];
        s1 += CtL[(p * 16 + cv) * 32 + hh];
      }
      s0 += AtL[(int)actL[tbl] * 32 + hh];
      float d0 = dirL[tbl * 4 + 0], d1 = dirL[tbl * 4 + 1];
      float d2 = dirL[tbl * 4 + 2], d3 = dirL[tbl * 4 + 3];
      s1 += d0 * WdL[hh] + d1 * WdL[32 + hh] + d2 * WdL[64 + hh] + d3 * WdL[96 + hh];
      s0 += rewL[tbl] * wrr + dnL[tbl] * wdr;
      float xv = fmaxf(s0 + s1, 0.f);
      xout[(size_t)(tb0 + tbl) * 256 + h0 + hh] = __float2bfloat16(xv);
    }
  }
}

// ---------------- persistent fused LSTM (no atomics in loop) ----------------
__global__ __launch_bounds__(256, 1) void k_lstm(
    const float* c0, const float* bh, float* out, char* ws) {
  __shared__ u16 W2T[65536];              // 128KB: [128 pc][512 k], XOR-swizzled
  __shared__ unsigned hstage[2][16 * 36]; // tagged h staging [slot][b][36-pad]

  u16* xseq = (u16*)(ws + WS_X);
  unsigned* hdb = (unsigned*)(ws + WS_HDB);  // tagged dwords [2][512 b][256 j]
  const u16* w2src = (const u16*)(ws + WS_W2T);

  const int tid = threadIdx.x;
  const int bid = blockIdx.x;
  const int c = bid & 31;             // cluster (batch slice)
  const int q = bid >> 5;             // hidden chunk (j in [q*32, q*32+32))
  const int b0 = c * 16;
  const int lane = tid & 63, wv = tid >> 6;
  const int G = lane >> 4, bl = lane & 15;

  {  // stage W2T slice (once)
    const s8v* src = (const s8v*)(w2src + (size_t)q * 65536);
    s8v* dst = (s8v*)W2T;
    for (int i = tid; i < 8192; i += 256) dst[i] = src[i];
  }
  __syncthreads();

  const int jt0 = wv * 2, jt1 = wv * 2 + 1;
  const int jl0 = jt0 * 4 + G, jl1 = jt1 * 4 + G;
  const int myhj0 = q * 32 + jl0, myhj1 = q * 32 + jl1;
  const unsigned swz = ((unsigned)(bl & 7)) << 4;
  const unsigned ab0 = ((unsigned)(jt0 * 16 + bl)) << 10;
  const unsigned ab1 = ((unsigned)(jt1 * 16 + bl)) << 10;

  float bh0r[4], bh1r[4];
#pragma unroll
  for (int r = 0; r < 4; ++r) {
    bh0r[r] = bh[r * 256 + myhj0];
    bh1r[r] = bh[r * 256 + myhj1];
  }
  float cst0 = c0[(size_t)(b0 + bl) * 256 + myhj0];
  float cst1 = c0[(size_t)(b0 + bl) * 256 + myhj1];

  float* out_cf = out + 458752;
  float* out_hf = out + 589824;

  for (int t = 0; t < 128; ++t) {
    // ---- 1) issue x-frag loads, then poll loads, all inline asm
    s8v xf[8];
    const u16* xr = xseq + ((size_t)t * 512 + (b0 + bl)) * 256 + 8 * G;
#pragma unroll
    for (int ks = 0; ks < 8; ++ks)
      asm volatile("global_load_dwordx4 %0, %1, off"
                   : "=v"(xf[ks]) : "v"(xr + ks * 32));

    U4 qv[16];
    const unsigned* hp = hdb + (size_t)(t & 1) * 131072u +
                         (size_t)(b0 + bl) * 256u + (unsigned)(G * 8);
#pragma unroll
    for (int i = 0; i < 16; ++i) {
      if ((i >> 1) != q || t == 0)   // own chunk comes from LDS when t>0
        asm volatile("global_load_dwordx4 %0, %1, off sc0 sc1"
                     : "=v"(qv[i].v4) : "v"(hp + (i >> 1) * 32 + (i & 1) * 4));
    }
    asm volatile("s_waitcnt vmcnt(14)" ::: "memory");
    __builtin_amdgcn_sched_barrier(0);

    // ---- 2) x-MFMAs overlap the first poll flight
    f4v acc0 = {0.f, 0.f, 0.f, 0.f};
    f4v acc1 = {0.f, 0.f, 0.f, 0.f};
#pragma unroll
    for (int ks = 0; ks < 8; ++ks) {
      unsigned k2 = (unsigned)(ks * 64 + G * 16);
      s8v a0 = *(const s8v*)((const char*)W2T + ((ab0 + k2) ^ swz));
      s8v a1 = *(const s8v*)((const char*)W2T + ((ab1 + k2) ^ swz));
      acc0 = __builtin_amdgcn_mfma_f32_16x16x32_bf16(a0, xf[ks], acc0, 0, 0, 0);
      acc1 = __builtin_amdgcn_mfma_f32_16x16x32_bf16(a1, xf[ks], acc1, 0, 0, 0);
    }
    asm volatile("s_waitcnt vmcnt(0)" ::: "memory");
    __builtin_amdgcn_sched_barrier(0);

    // ---- 3) tag check + re-poll (s_sleep backoff)
    const unsigned tq = (unsigned)t;
    bool ok = true;
#pragma unroll
    for (int i = 0; i < 16; ++i) {
      if ((i >> 1) == q && t != 0) continue;
#pragma unroll
      for (int c2 = 0; c2 < 4; ++c2) ok &= ((qv[i].u[c2] >> 16) == tq);
    }
    while (!ok) {
      __builtin_amdgcn_s_sleep(2);
#pragma unroll
      for (int i = 0; i < 16; ++i) {
        if ((i >> 1) != q || t == 0)
          asm volatile("global_load_dwordx4 %0, %1, off sc0 sc1"
                       : "=v"(qv[i].v4) : "v"(hp + (i >> 1) * 32 + (i & 1) * 4));
      }
      asm volatile("s_waitcnt vmcnt(0)" ::: "memory");
      __builtin_amdgcn_sched_barrier(0);
      ok = true;
#pragma unroll
      for (int i = 0; i < 16; ++i) {
        if ((i >> 1) == q && t != 0) continue;
#pragma unroll
        for (int c2 = 0; c2 < 4; ++c2) ok &= ((qv[i].u[c2] >> 16) == tq);
      }
    }

    // ---- 4) h-MFMAs (own chunk from hstage[t&1])
#pragma unroll
    for (int ks = 0; ks < 8; ++ks) {
      union { s8v v; unsigned u[4]; } bu;
      if (ks == q && t != 0) {
        const unsigned* hs = &hstage[t & 1][bl * 36 + G * 8];
        bu.u[0] = (hs[0] & 0xffffu) | (hs[1] << 16);
        bu.u[1] = (hs[2] & 0xffffu) | (hs[3] << 16);
        bu.u[2] = (hs[4] & 0xffffu) | (hs[5] << 16);
        bu.u[3] = (hs[6] & 0xffffu) | (hs[7] << 16);
      } else {
        const unsigned* pa = qv[ks * 2].u;
        const unsigned* pb = qv[ks * 2 + 1].u;
        bu.u[0] = (pa[0] & 0xffffu) | (pa[1] << 16);
        bu.u[1] = (pa[2] & 0xffffu) | (pa[3] << 16);
        bu.u[2] = (pb[0] & 0xffffu) | (pb[1] << 16);
        bu.u[3] = (pb[2] & 0xffffu) | (pb[3] << 16);
      }
      unsigned k2 = (unsigned)((ks + 8) * 64 + G * 16);
      s8v a0 = *(const s8v*)((const char*)W2T + ((ab0 + k2) ^ swz));
      s8v a1 = *(const s8v*)((const char*)W2T + ((ab1 + k2) ^ swz));
      acc0 = __builtin_amdgcn_mfma_f32_16x16x32_bf16(a0, bu.v, acc0, 0, 0, 0);
      acc1 = __builtin_amdgcn_mfma_f32_16x16x32_bf16(a1, bu.v, acc1, 0, 0, 0);
    }

    // ---- 5) gates (lane-local: acc[r] = gate r of (b0+bl, myhj))
    float zi0 = acc0[0] + bh0r[0], zf0 = acc0[1] + bh0r[1];
    float zg0 = acc0[2] + bh0r[2], zo0 = acc0[3] + bh0r[3];
    float cn0 = sigm_(zf0) * cst0 + sigm_(zi0) * tanh_(zg0);
    float hn0 = sigm_(zo0) * tanh_(cn0);
    cst0 = cn0;
    float zi1 = acc1[0] + bh1r[0], zf1 = acc1[1] + bh1r[1];
    float zg1 = acc1[2] + bh1r[2], zo1 = acc1[3] + bh1r[3];
    float cn1 = sigm_(zf1) * cst1 + sigm_(zi1) * tanh_(zg1);
    float hn1 = sigm_(zo1) * tanh_(cn1);
    cst1 = cn1;

    // ---- 6) early publish: per-lane tagged sc01 stores straight from regs
    const int wslot = (t + 1) & 1;
    if (t < 127) {
      __hip_bfloat16 hb0 = __float2bfloat16(hn0);
      __hip_bfloat16 hb1 = __float2bfloat16(hn1);
      unsigned d0 = ((unsigned)(t + 1) << 16) | (unsigned)*(u16*)&hb0;
      unsigned d1 = ((unsigned)(t + 1) << 16) | (unsigned)*(u16*)&hb1;
      unsigned* hw = hdb + (size_t)wslot * 131072u + (size_t)(b0 + bl) * 256u;
      asm volatile("global_store_dword %0, %1, off sc0 sc1"
                   :: "v"(hw + myhj0), "v"(d0) : "memory");
      asm volatile("global_store_dword %0, %1, off sc0 sc1"
                   :: "v"(hw + myhj1), "v"(d1) : "memory");
      hstage[wslot][bl * 36 + jl0] = d0;
      hstage[wslot][bl * 36 + jl1] = d1;
    } else {
      size_t o = (size_t)(b0 + bl) * 256;
      out_cf[o + myhj0] = cst0;
      out_cf[o + myhj1] = cst1;
      out_hf[o + myhj0] = hn0;
      out_hf[o + myhj1] = hn1;
    }

    // ---- 7) h_seq[t-1] -> slot t-1 (wave 1; t>=1)
    // Safe: tag-t detect => all 8 cluster peers finished step-(t-1) x-reads
    // of slot t-1. hstage[t&1] (h_{t-1}) is stable until step t+1.
    if (wv == 1 && t >= 1) {
      int b_ = lane >> 2, o8 = (lane & 3) * 8;
      const unsigned* hs = &hstage[t & 1][b_ * 36 + o8];
      U4 pk;
      pk.u[0] = (hs[0] & 0xffffu) | (hs[1] << 16);
      pk.u[1] = (hs[2] & 0xffffu) | (hs[3] << 16);
      pk.u[2] = (hs[4] & 0xffffu) | (hs[5] << 16);
      pk.u[3] = (hs[6] & 0xffffu) | (hs[7] << 16);
      u16* hd = xseq + ((size_t)(t - 1) * 512 + (b0 + b_)) * 256 +
                (unsigned)(q * 32 + o8);
      *(u4v*)hd = pk.v4;
    }

    __syncthreads();   // hstage[wslot] complete for next step's own-chunk read
  }
}

// ---------------- heads: logits/values from h_seq ---------------------------
__global__ __launch_bounds__(256) void k_head(
    const float* Wpi, const float* bpi, const float* Wv, const float* bv,
    float* out, const char* ws) {
  __shared__ float WL[256][8];
  int tid = threadIdx.x;
#pragma unroll
  for (int a = 0; a < 8; ++a)
    WL[tid][a] = (a < 6) ? Wpi[tid * 6 + a] : ((a == 6) ? Wv[tid] : 0.f);
  __syncthreads();

  int row = blockIdx.x * 256 + tid;      // tb in [0, 65536)
  int t = row >> 9, b = row & 511;
  float acc[7] = {0.f, 0.f, 0.f, 0.f, 0.f, 0.f, 0.f};
  if (t == 127) {
    const float* hr = out + 589824 + (size_t)b * 256;
    for (int h = 0; h < 256; ++h) {
      float f = hr[h];
#pragma unroll
      for (int a = 0; a < 7; ++a) acc[a] += f * WL[h][a];
    }
  } else {
    const u16* hr = (const u16*)(ws + WS_X) + (size_t)row * 256;
    for (int k0 = 0; k0 < 32; ++k0) {
      U4 v;
      v.v4 = *(const u4v*)(hr + k0 * 8);
#pragma unroll
      for (int e = 0; e < 8; ++e) {
        unsigned hw = (e & 1) ? (v.u[e >> 1] >> 16) : (v.u[e >> 1] & 0xffffu);
        float f = __uint_as_float(hw << 16);
        int h = k0 * 8 + e;
#pragma unroll
        for (int a = 0; a < 7; ++a) acc[a] += f * WL[h][a];
      }
    }
  }
  float* out_logits = out;
  float* out_values = out + 393216;
#pragma unroll
  for (int a = 0; a < 6; ++a) out_logits[(size_t)row * 6 + a] = acc[a] + bpi[a];
  out_values[row] = acc[6] + bv[0];
}

extern "C" void kernel_launch(void* const* d_in, const int* in_sizes, int n_in,
                              void* d_out, int out_size, void* d_ws, size_t ws_size,
                              hipStream_t stream) {
  const int*   obs_img     = (const int*)d_in[0];
  const float* obs_dir     = (const float*)d_in[1];
  const int*   prev_action = (const int*)d_in[2];
  const float* prev_reward = (const float*)d_in[3];
  const float* done        = (const float*)d_in[4];
  const float* c0          = (const float*)d_in[5];
  const float* h0          = (const float*)d_in[6];
  const float* tile_emb    = (const float*)d_in[7];
  const float* color_emb   = (const float*)d_in[8];
  const float* action_emb  = (const float*)d_in[9];
  const float* Wdir        = (const float*)d_in[10];
  const float* bdir        = (const float*)d_in[11];
  const float* W1          = (const float*)d_in[12];
  const float* b1          = (const float*)d_in[13];
  const float* Wx          = (const float*)d_in[14];
  const float* Wh          = (const float*)d_in[15];
  const float* bh          = (const float*)d_in[16];
  const float* Wpi         = (const float*)d_in[17];
  const float* bpi         = (const float*)d_in[18];
  const float* Wv          = (const float*)d_in[19];
  const float* bv          = (const float*)d_in[20];
  (void)in_sizes; (void)n_in; (void)out_size; (void)ws_size;

  char* ws = (char*)d_ws;
  float* out = (float*)d_out;

  // kill stale tags every launch (0xAAAA never matches a real tag 0..128)
  (void)hipMemsetAsync(ws + WS_HDB, 0xAA, 1048576u, stream);
  k_prep<<<1456, 256, 0, stream>>>(tile_emb, color_emb, action_emb, Wdir, bdir,
                                   W1, b1, Wx, Wh, h0, ws);
  k_x<<<512, 512, 0, stream>>>(obs_img, obs_dir, prev_action, prev_reward, done, ws);
  k_lstm<<<256, 256, 0, stream>>>(c0, bh, out, ws);
  k_head<<<256, 256, 0, stream>>>(Wpi, bpi, Wv, bv, out, ws);
}

// Round 14
// 1271.390 us; speedup vs baseline: 3.1554x; 1.0179x over previous
//
#include <hip/hip_runtime.h>
#include <hip/hip_bf16.h>

// RL2 LSTM fused kernel, round 14.
// = r10 (proven 818-880us k_lstm; in-loop logits atomics restored -- r13
// proved they were ~free) + ONE addition: a single-dword per-(parity,cluster)
// ready-counter as an ADVISORY detection gate.
//   producer: after the per-step barrier (compiler drain => publish stores
//             complete), tid0 fire-and-forget atomic_add on cnt[(t+1)&1][c].
//   consumer: bounded spin (16K iters, 1 cache line/round ~0.3us vs the
//             1.4us 56-line tag round) until cnt >= 8*((t+1)>>1), then falls
//             through to r10's EXACT tag loop -- still the sole correctness
//             gate. Counter ahead of data => tags catch; counter stuck =>
//             bound expires => proven loop proceeds. Cannot hang.
// Theory: detection granularity (full 56-line round + vmcnt(0) per sample)
// is the bulk of the 6.4us/step; a 1-line spin samples 4-5x faster.

#define WS_TT   0u
#define WS_CT   409600u
#define WS_AT   819200u
#define WS_WD1  825344u
#define WS_B1T  829440u
#define WS_WRW  830464u
#define WS_WDN  831488u
#define WS_W2T  1048576u   // 1024 pc x 512 k bf16, swizzled: 1MB
#define WS_HDB  2097152u   // ring: 2 x 512 x 256 tagged dwords = 1MB
#define WS_FLG  3145728u   // cnt[2][32] dwords = 256B
#define WS_X    4194304u   // 65536 x 256 bf16 = 32MB

typedef __attribute__((ext_vector_type(8))) short s8v;
typedef __attribute__((ext_vector_type(4))) float f4v;
typedef __attribute__((ext_vector_type(4))) unsigned u4v;
typedef unsigned short u16;
typedef unsigned char u8;

union U4 { u4v v4; unsigned u[4]; };

__device__ __forceinline__ float sigm_(float x) {
  return __builtin_amdgcn_rcpf(1.f + __expf(-x));
}
__device__ __forceinline__ float tanh_(float x) {
  return 1.f - 2.f * __builtin_amdgcn_rcpf(1.f + __expf(2.f * x));
}

// ---------------- fused prep: tables + W2T + h0/bias init -------------------
__global__ __launch_bounds__(256) void k_prep(
    const float* tile_emb, const float* color_emb, const float* action_emb,
    const float* Wdir, const float* bdir, const float* W1, const float* b1,
    const float* Wx, const float* Wh, const float* h0, const float* bpi,
    const float* bv, float* out, char* ws) {
  int id = blockIdx.x;
  int h = threadIdx.x;
  if (id < 816) {
    // ---- encoder tables ----
    float* TT  = (float*)(ws + WS_TT);
    float* CT  = (float*)(ws + WS_CT);
    float* AT  = (float*)(ws + WS_AT);
    float* WD1 = (float*)(ws + WS_WD1);
    float* B1T = (float*)(ws + WS_B1T);
    float* WRW = (float*)(ws + WS_WRW);
    float* WDN = (float*)(ws + WS_WDN);
    if (id < 400) {                 // Ttab[p][v][h]
      int p = id >> 4, v = id & 15;
      float s = 0.f;
#pragma unroll
      for (int e = 0; e < 16; ++e) s += tile_emb[v * 16 + e] * W1[(p * 32 + e) * 256 + h];
      TT[id * 256 + h] = s;
    } else if (id < 800) {          // Ctab[p][v][h]
      int p = (id - 400) >> 4, v = id & 15;
      float s = 0.f;
#pragma unroll
      for (int e = 0; e < 16; ++e) s += color_emb[v * 16 + e] * W1[(p * 32 + 16 + e) * 256 + h];
      CT[(id - 400) * 256 + h] = s;
    } else {
      int r = id - 800;
      if (r < 6) {
        float s = 0.f;
#pragma unroll
        for (int e = 0; e < 16; ++e) s += action_emb[r * 16 + e] * W1[(816 + e) * 256 + h];
        AT[r * 256 + h] = s;
      } else if (r < 10) {
        int d = r - 6;
        float s = 0.f;
#pragma unroll
        for (int e = 0; e < 16; ++e) s += Wdir[d * 16 + e] * W1[(800 + e) * 256 + h];
        WD1[d * 256 + h] = s;
      } else if (r == 10) {
        float s = b1[h];
#pragma unroll
        for (int e = 0; e < 16; ++e) s += bdir[e] * W1[(800 + e) * 256 + h];
        B1T[h] = s;
      } else if (r == 11) {
        WRW[h] = W1[832 * 256 + h];
      } else if (r == 12) {
        WDN[h] = W1[833 * 256 + h];
      }
    }
  } else if (id < 944) {
    // ---- W2T = [Wx;Wh]^T bf16, pc-permuted, LDS-XOR-preswizzled ----
    int wb = id - 816;
#pragma unroll
    for (int kk = 0; kk < 4; ++kk) {
      int k = wb * 4 + kk;
      const float* row = (k < 256) ? (Wx + (size_t)k * 1024)
                                   : (Wh + (size_t)(k - 256) * 1024);
      float4 v4 = *(const float4*)(row + h * 4);
      float vv[4] = {v4.x, v4.y, v4.z, v4.w};
#pragma unroll
      for (int e = 0; e < 4; ++e) {
        int n = h * 4 + e;
        int gate = n >> 8, rem = n & 255;
        int q = rem >> 5, jl = rem & 31;
        int pcl = (jl >> 2) * 16 + (jl & 3) * 4 + gate;
        unsigned byteoff = ((unsigned)(pcl << 10) + (unsigned)(k << 1)) ^
                           (((unsigned)(pcl & 7)) << 4);
        __hip_bfloat16 bv16 = __float2bfloat16(vv[e]);
        *(u16*)(ws + WS_W2T + (size_t)q * 131072u + byteoff) = *(u16*)&bv16;
      }
    }
  } else {
    // ---- misc init ----
    int mb = id - 944;
    int i = mb * 256 + h;
    if (mb < 512) {                       // h0 -> tagged dwords, tag 0
      unsigned* hdb = (unsigned*)(ws + WS_HDB);
      __hip_bfloat16 hb = __float2bfloat16(h0[i]);
      hdb[i] = (unsigned)*(u16*)&hb;      // tag = 0 in high bits
    } else if (mb < 2048) {               // logits = bpi
      int j = i - 131072;
      out[j] = bpi[j % 6];
    } else {                              // values = bv
      int j = i - 524288;
      out[393216 + j] = bv[0];
    }
  }
}

// ---------------- x = relu(enc @ W1 + b1)  via tables -----------------------
__global__ __launch_bounds__(512, 1) void k_x(
    const int* obs_img, const float* obs_dir, const int* prev_action,
    const float* prev_reward, const float* done, char* ws) {
  __shared__ float TtL[12800];   // [25*16][32]
  __shared__ float CtL[12800];
  __shared__ float AtL[192];
  __shared__ float WdL[128];
  __shared__ u8 pkT[6400];       // [256 tb][25]
  __shared__ u8 pkC[6400];
  __shared__ u8 actL[256];
  __shared__ float rewL[256];
  __shared__ float dnL[256];
  __shared__ float dirL[1024];

  const float* TT  = (const float*)(ws + WS_TT);
  const float* CT  = (const float*)(ws + WS_CT);
  const float* AT  = (const float*)(ws + WS_AT);
  const float* WD1 = (const float*)(ws + WS_WD1);
  const float* B1T = (const float*)(ws + WS_B1T);
  const float* WRW = (const float*)(ws + WS_WRW);
  const float* WDN = (const float*)(ws + WS_WDN);
  __hip_bfloat16* xout = (__hip_bfloat16*)(ws + WS_X);

  int bid = blockIdx.x;          // 512 blocks
  int slice = bid & 7, grp = bid >> 3;   // 64 groups x 1024 tb
  int h0 = slice * 32;
  int tid = threadIdx.x;
  int sub = tid >> 5, hh = tid & 31;

  for (int e = tid; e < 12800; e += 512) {
    int pv = e >> 5, k = e & 31;
    TtL[e] = TT[pv * 256 + h0 + k];
    CtL[e] = CT[pv * 256 + h0 + k];
  }
  for (int e = tid; e < 192; e += 512) AtL[e] = AT[(e >> 5) * 256 + h0 + (e & 31)];
  for (int e = tid; e < 128; e += 512) WdL[e] = WD1[(e >> 5) * 256 + h0 + (e & 31)];
  float b1r = B1T[h0 + hh], wrr = WRW[h0 + hh], wdr = WDN[h0 + hh];

  for (int cg = 0; cg < 4; ++cg) {
    int tb0 = grp * 1024 + cg * 256;
    __syncthreads();
    for (int e = tid; e < 6400; e += 512) {
      int tbl = e / 25, p = e - tbl * 25;
      int base = ((tb0 + tbl) * 25 + p) * 2;
      pkT[e] = (u8)obs_img[base];
      pkC[e] = (u8)obs_img[base + 1];
    }
    for (int e = tid; e < 256; e += 512) {
      actL[e] = (u8)prev_action[tb0 + e];
      rewL[e] = prev_reward[tb0 + e];
      dnL[e]  = done[tb0 + e];
    }
    for (int e = tid; e < 1024; e += 512) dirL[e] = obs_dir[(size_t)tb0 * 4 + e];
    __syncthreads();

    for (int pass = 0; pass < 16; ++pass) {
      int tbl = pass * 16 + sub;
      float s0 = b1r, s1 = 0.f;
#pragma unroll
      for (int p = 0; p < 25; ++p) {
        int tv = pkT[tbl * 25 + p];
        int cv = pkC[tbl * 25 + p];
        s0 += TtL[(p * 16 + tv) * 32 + hh];
        s1 += CtL[(p * 16 + cv) * 32 + hh];
      }
      s0 += AtL[(int)actL[tbl] * 32 + hh];
      float d0 = dirL[tbl * 4 + 0], d1 = dirL[tbl * 4 + 1];
      float d2 = dirL[tbl * 4 + 2], d3 = dirL[tbl * 4 + 3];
      s1 += d0 * WdL[hh] + d1 * WdL[32 + hh] + d2 * WdL[64 + hh] + d3 * WdL[96 + hh];
      s0 += rewL[tbl] * wrr + dnL[tbl] * wdr;
      float xv = fmaxf(s0 + s1, 0.f);
      xout[(size_t)(tb0 + tbl) * 256 + h0 + hh] = __float2bfloat16(xv);
    }
  }
}

// ---------------- persistent fused LSTM (counter-gated detect) --------------
__global__ __launch_bounds__(256, 1) void k_lstm(
    const float* c0, const float* bh, const float* Wpi, const float* Wv,
    float* out, char* ws) {
  __shared__ u16 W2T[65536];            // 128KB: [128 pc][512 k], XOR-swizzled
  __shared__ float WpiL[32][8];         // [j-local][a]; a=6 is Wv
  __shared__ float part[2][4][16][8];   // logits partials, dbuf by t&1
  __shared__ unsigned hstage[2][16 * 36]; // tagged h staging [slot][b][36-pad]

  const u16* xbf = (const u16*)(ws + WS_X);
  unsigned* hdb = (unsigned*)(ws + WS_HDB);  // tagged dwords [2][512 b][256 j]
  unsigned* cnt = (unsigned*)(ws + WS_FLG);  // ready counters [2][32]
  const u16* w2src = (const u16*)(ws + WS_W2T);

  const int tid = threadIdx.x;
  const int bid = blockIdx.x;
  const int c = bid & 31;             // cluster (batch slice)
  const int q = bid >> 5;             // hidden chunk (j in [q*32, q*32+32))
  const int b0 = c * 16;
  const int lane = tid & 63, wv = tid >> 6;
  const int G = lane >> 4, bl = lane & 15;

  {  // stage W2T slice (once)
    const s8v* src = (const s8v*)(w2src + (size_t)q * 65536);
    s8v* dst = (s8v*)W2T;
    for (int i = tid; i < 8192; i += 256) dst[i] = src[i];
  }
  {
    int jl = tid >> 3, a = tid & 7;
    int j = q * 32 + jl;
    WpiL[jl][a] = (a < 6) ? Wpi[j * 6 + a] : ((a == 6) ? Wv[j] : 0.f);
  }
  __syncthreads();

  const int jt0 = wv * 2, jt1 = wv * 2 + 1;
  const int jl0 = jt0 * 4 + G, jl1 = jt1 * 4 + G;
  const int myhj0 = q * 32 + jl0, myhj1 = q * 32 + jl1;
  const unsigned swz = ((unsigned)(bl & 7)) << 4;
  const unsigned ab0 = ((unsigned)(jt0 * 16 + bl)) << 10;
  const unsigned ab1 = ((unsigned)(jt1 * 16 + bl)) << 10;

  float bh0r[4], bh1r[4];
#pragma unroll
  for (int r = 0; r < 4; ++r) {
    bh0r[r] = bh[r * 256 + myhj0];
    bh1r[r] = bh[r * 256 + myhj1];
  }
  float cst0 = c0[(size_t)(b0 + bl) * 256 + myhj0];
  float cst1 = c0[(size_t)(b0 + bl) * 256 + myhj1];

  float* out_logits = out;
  float* out_values = out + 393216;
  float* out_cf = out + 458752;
  float* out_hf = out + 589824;

  for (int t = 0; t < 128; ++t) {
    // ---- 1) issue x-frag loads, then (speculative) poll loads
    s8v xf[8];
    const u16* xr = xbf + ((size_t)t * 512 + (b0 + bl)) * 256 + 8 * G;
#pragma unroll
    for (int ks = 0; ks < 8; ++ks)
      asm volatile("global_load_dwordx4 %0, %1, off"
                   : "=v"(xf[ks]) : "v"(xr + ks * 32));

    U4 qv[16];
    const unsigned* hp = hdb + (size_t)(t & 1) * 131072u +
                         (size_t)(b0 + bl) * 256u + (unsigned)(G * 8);
#pragma unroll
    for (int i = 0; i < 16; ++i) {
      if ((i >> 1) != q || t == 0)   // own chunk comes from LDS when t>0
        asm volatile("global_load_dwordx4 %0, %1, off sc0 sc1"
                     : "=v"(qv[i].v4) : "v"(hp + (i >> 1) * 32 + (i & 1) * 4));
    }
    asm volatile("s_waitcnt vmcnt(14)" ::: "memory");
    __builtin_amdgcn_sched_barrier(0);

    // ---- 2) x-MFMAs overlap the poll flight
    f4v acc0 = {0.f, 0.f, 0.f, 0.f};
    f4v acc1 = {0.f, 0.f, 0.f, 0.f};
#pragma unroll
    for (int ks = 0; ks < 8; ++ks) {
      unsigned k2 = (unsigned)(ks * 64 + G * 16);
      s8v a0 = *(const s8v*)((const char*)W2T + ((ab0 + k2) ^ swz));
      s8v a1 = *(const s8v*)((const char*)W2T + ((ab1 + k2) ^ swz));
      acc0 = __builtin_amdgcn_mfma_f32_16x16x32_bf16(a0, xf[ks], acc0, 0, 0, 0);
      acc1 = __builtin_amdgcn_mfma_f32_16x16x32_bf16(a1, xf[ks], acc1, 0, 0, 0);
    }

    // ---- 2b) NEW: bounded 1-dword ready-counter spin (advisory only)
    if (t > 0) {
      const unsigned tgt = 8u * (((unsigned)t + 1u) >> 1);
      const unsigned* cp = cnt + (t & 1) * 32 + c;
      unsigned cv = 0;
      for (int spin = 0; spin < 16384; ++spin) {
        asm volatile("global_load_dword %0, %1, off sc0 sc1" : "=v"(cv) : "v"(cp));
        asm volatile("s_waitcnt vmcnt(0)" ::: "memory");
        __builtin_amdgcn_sched_barrier(0);
        if (cv >= tgt) break;
      }
    } else {
      asm volatile("s_waitcnt vmcnt(0)" ::: "memory");
      __builtin_amdgcn_sched_barrier(0);
    }

    // ---- 3) tag check + re-poll (r10's proven loop -- the true gate)
    const unsigned tq = (unsigned)t;
    bool ok = true;
#pragma unroll
    for (int i = 0; i < 16; ++i) {
      if ((i >> 1) == q && t != 0) continue;
#pragma unroll
      for (int c2 = 0; c2 < 4; ++c2) ok &= ((qv[i].u[c2] >> 16) == tq);
    }
    while (!ok) {
#pragma unroll
      for (int i = 0; i < 16; ++i) {
        if ((i >> 1) != q || t == 0)
          asm volatile("global_load_dwordx4 %0, %1, off sc0 sc1"
                       : "=v"(qv[i].v4) : "v"(hp + (i >> 1) * 32 + (i & 1) * 4));
      }
      asm volatile("s_waitcnt vmcnt(0)" ::: "memory");
      __builtin_amdgcn_sched_barrier(0);
      ok = true;
#pragma unroll
      for (int i = 0; i < 16; ++i) {
        if ((i >> 1) == q && t != 0) continue;
#pragma unroll
        for (int c2 = 0; c2 < 4; ++c2) ok &= ((qv[i].u[c2] >> 16) == tq);
      }
    }

    // ---- 4) h-MFMAs (own chunk from hstage[t&1])
#pragma unroll
    for (int ks = 0; ks < 8; ++ks) {
      union { s8v v; unsigned u[4]; } bu;
      if (ks == q && t != 0) {
        const unsigned* hs = &hstage[t & 1][bl * 36 + G * 8];
        bu.u[0] = (hs[0] & 0xffffu) | (hs[1] << 16);
        bu.u[1] = (hs[2] & 0xffffu) | (hs[3] << 16);
        bu.u[2] = (hs[4] & 0xffffu) | (hs[5] << 16);
        bu.u[3] = (hs[6] & 0xffffu) | (hs[7] << 16);
      } else {
        const unsigned* pa = qv[ks * 2].u;
        const unsigned* pb = qv[ks * 2 + 1].u;
        bu.u[0] = (pa[0] & 0xffffu) | (pa[1] << 16);
        bu.u[1] = (pa[2] & 0xffffu) | (pa[3] << 16);
        bu.u[2] = (pb[0] & 0xffffu) | (pb[1] << 16);
        bu.u[3] = (pb[2] & 0xffffu) | (pb[3] << 16);
      }
      unsigned k2 = (unsigned)((ks + 8) * 64 + G * 16);
      s8v a0 = *(const s8v*)((const char*)W2T + ((ab0 + k2) ^ swz));
      s8v a1 = *(const s8v*)((const char*)W2T + ((ab1 + k2) ^ swz));
      acc0 = __builtin_amdgcn_mfma_f32_16x16x32_bf16(a0, bu.v, acc0, 0, 0, 0);
      acc1 = __builtin_amdgcn_mfma_f32_16x16x32_bf16(a1, bu.v, acc1, 0, 0, 0);
    }

    // ---- 5) gates (lane-local: acc[r] = gate r of (b0+bl, myhj))
    float zi0 = acc0[0] + bh0r[0], zf0 = acc0[1] + bh0r[1];
    float zg0 = acc0[2] + bh0r[2], zo0 = acc0[3] + bh0r[3];
    float cn0 = sigm_(zf0) * cst0 + sigm_(zi0) * tanh_(zg0);
    float hn0 = sigm_(zo0) * tanh_(cn0);
    cst0 = cn0;
    float zi1 = acc1[0] + bh1r[0], zf1 = acc1[1] + bh1r[1];
    float zg1 = acc1[2] + bh1r[2], zo1 = acc1[3] + bh1r[3];
    float cn1 = sigm_(zf1) * cst1 + sigm_(zi1) * tanh_(zg1);
    float hn1 = sigm_(zo1) * tanh_(cn1);
    cst1 = cn1;

    // ---- 6) early publish: per-lane tagged sc01 stores straight from regs
    const int wslot = (t + 1) & 1, pt = t & 1;
    if (t < 127) {
      __hip_bfloat16 hb0 = __float2bfloat16(hn0);
      __hip_bfloat16 hb1 = __float2bfloat16(hn1);
      unsigned d0 = ((unsigned)(t + 1) << 16) | (unsigned)*(u16*)&hb0;
      unsigned d1 = ((unsigned)(t + 1) << 16) | (unsigned)*(u16*)&hb1;
      unsigned* hw = hdb + (size_t)wslot * 131072u + (size_t)(b0 + bl) * 256u;
      asm volatile("global_store_dword %0, %1, off sc0 sc1"
                   :: "v"(hw + myhj0), "v"(d0) : "memory");
      asm volatile("global_store_dword %0, %1, off sc0 sc1"
                   :: "v"(hw + myhj1), "v"(d1) : "memory");
      hstage[wslot][bl * 36 + jl0] = d0;
      hstage[wslot][bl * 36 + jl1] = d1;
    } else {
      size_t o = (size_t)(b0 + bl) * 256;
      out_cf[o + myhj0] = cst0;
      out_cf[o + myhj1] = cst1;
      out_hf[o + myhj0] = hn0;
      out_hf[o + myhj1] = hn1;
    }

    // ---- 7) logits/value partials (overlaps publish flight)
    float pl[7];
#pragma unroll
    for (int a = 0; a < 7; ++a) {
      float s = hn0 * WpiL[jl0][a] + hn1 * WpiL[jl1][a];
      s += __shfl_xor(s, 16, 64);
      s += __shfl_xor(s, 32, 64);
      pl[a] = s;
    }
    if (lane < 16) {
#pragma unroll
      for (int a = 0; a < 7; ++a) part[pt][wv][bl][a] = pl[a];
    }

    __syncthreads();   // compiler drains vmcnt => publish stores complete

    // ---- 7b) NEW: ready-counter increment (fire-and-forget, tid 0)
    if (t < 127 && tid == 0) {
      __hip_atomic_fetch_add(cnt + wslot * 32 + c, 1u, __ATOMIC_RELAXED,
                             __HIP_MEMORY_SCOPE_SYSTEM);
    }

    // ---- 8) logits adds (waves 2-3)
    if (tid >= 128) {
      int i2 = tid - 128, b_ = i2 >> 3, a_ = i2 & 7;
      if (a_ < 7) {
        float s = part[pt][0][b_][a_] + part[pt][1][b_][a_] +
                  part[pt][2][b_][a_] + part[pt][3][b_][a_];
        if (a_ < 6)
          atomicAdd(out_logits + ((size_t)t * 512 + b0 + b_) * 6 + a_, s);
        else
          atomicAdd(out_values + (size_t)t * 512 + b0 + b_, s);
      }
    }
  }
}

extern "C" void kernel_launch(void* const* d_in, const int* in_sizes, int n_in,
                              void* d_out, int out_size, void* d_ws, size_t ws_size,
                              hipStream_t stream) {
  const int*   obs_img     = (const int*)d_in[0];
  const float* obs_dir     = (const float*)d_in[1];
  const int*   prev_action = (const int*)d_in[2];
  const float* prev_reward = (const float*)d_in[3];
  const float* done        = (const float*)d_in[4];
  const float* c0          = (const float*)d_in[5];
  const float* h0          = (const float*)d_in[6];
  const float* tile_emb    = (const float*)d_in[7];
  const float* color_emb   = (const float*)d_in[8];
  const float* action_emb  = (const float*)d_in[9];
  const float* Wdir        = (const float*)d_in[10];
  const float* bdir        = (const float*)d_in[11];
  const float* W1          = (const float*)d_in[12];
  const float* b1          = (const float*)d_in[13];
  const float* Wx          = (const float*)d_in[14];
  const float* Wh          = (const float*)d_in[15];
  const float* bh          = (const float*)d_in[16];
  const float* Wpi         = (const float*)d_in[17];
  const float* bpi         = (const float*)d_in[18];
  const float* Wv          = (const float*)d_in[19];
  const float* bv          = (const float*)d_in[20];
  (void)in_sizes; (void)n_in; (void)out_size; (void)ws_size;

  char* ws = (char*)d_ws;
  float* out = (float*)d_out;

  // stale-tag kill (0xAA) + ready-counter reset (0) every launch
  (void)hipMemsetAsync(ws + WS_HDB, 0xAA, 1048576u, stream);
  (void)hipMemsetAsync(ws + WS_FLG, 0, 256u, stream);
  k_prep<<<3248, 256, 0, stream>>>(tile_emb, color_emb, action_emb, Wdir, bdir,
                                   W1, b1, Wx, Wh, h0, bpi, bv, out, ws);
  k_x<<<512, 512, 0, stream>>>(obs_img, obs_dir, prev_action, prev_reward, done, ws);
  k_lstm<<<256, 256, 0, stream>>>(c0, bh, Wpi, Wv, out, ws);
}

// Round 15
// 1012.857 us; speedup vs baseline: 3.9608x; 1.2553x over previous
//
#include <hip/hip_runtime.h>
#include <hip/hip_bf16.h>

// RL2 LSTM fused kernel, round 15.
// = round 10 VERBATIM (best known: 1023.8us total, k_lstm ~820us) + one
// zero-risk change: the 1MB hdb memset (SDMA, stream-serial ~10-20us) is
// folded into k_prep -- slot 0 is fully overwritten by the h0-init blocks,
// 512 new blocks fill slot 1 with 0xAA. k_lstm byte-identical to r10.
//
// Why revert: 8 A/B experiments on the cross-block exchange (backoff r8,
// early-issue r10A, round-overlap r10B, rotation r9, single-reader r5-7,
// XCD-local r11, no-atomics r13, counter-gate r14) leave one standing
// mechanism: ~5-6us cross-XCD store-visibility + detection per sequential
// step. 128 steps x ~6us ~= 770us is the floor of this decomposition;
// the communication-free alternative (r12) is bounded by per-CU L2 BW at
// ~29us/step -- strictly worse.

#define WS_TT   0u
#define WS_CT   409600u
#define WS_AT   819200u
#define WS_WD1  825344u
#define WS_B1T  829440u
#define WS_WRW  830464u
#define WS_WDN  831488u
#define WS_W2T  1048576u   // 1024 pc x 512 k bf16, swizzled: 1MB
#define WS_HDB  2097152u   // ring: 2 x 512 x 256 tagged dwords = 1MB
#define WS_X    4194304u   // 65536 x 256 bf16 = 32MB
#define WS_NEED (WS_X + 33554432u)

typedef __attribute__((ext_vector_type(8))) short s8v;
typedef __attribute__((ext_vector_type(4))) float f4v;
typedef __attribute__((ext_vector_type(4))) unsigned u4v;
typedef unsigned short u16;
typedef unsigned char u8;

union U4 { u4v v4; unsigned u[4]; };

__device__ __forceinline__ float sigm_(float x) {
  return __builtin_amdgcn_rcpf(1.f + __expf(-x));
}
__device__ __forceinline__ float tanh_(float x) {
  return 1.f - 2.f * __builtin_amdgcn_rcpf(1.f + __expf(2.f * x));
}

// ---------------- fused prep: tables + W2T + h0/bias init + hdb fill --------
__global__ __launch_bounds__(256) void k_prep(
    const float* tile_emb, const float* color_emb, const float* action_emb,
    const float* Wdir, const float* bdir, const float* W1, const float* b1,
    const float* Wx, const float* Wh, const float* h0, const float* bpi,
    const float* bv, float* out, char* ws) {
  int id = blockIdx.x;
  int h = threadIdx.x;
  if (id < 816) {
    // ---- encoder tables ----
    float* TT  = (float*)(ws + WS_TT);
    float* CT  = (float*)(ws + WS_CT);
    float* AT  = (float*)(ws + WS_AT);
    float* WD1 = (float*)(ws + WS_WD1);
    float* B1T = (float*)(ws + WS_B1T);
    float* WRW = (float*)(ws + WS_WRW);
    float* WDN = (float*)(ws + WS_WDN);
    if (id < 400) {                 // Ttab[p][v][h]
      int p = id >> 4, v = id & 15;
      float s = 0.f;
#pragma unroll
      for (int e = 0; e < 16; ++e) s += tile_emb[v * 16 + e] * W1[(p * 32 + e) * 256 + h];
      TT[id * 256 + h] = s;
    } else if (id < 800) {          // Ctab[p][v][h]
      int p = (id - 400) >> 4, v = id & 15;
      float s = 0.f;
#pragma unroll
      for (int e = 0; e < 16; ++e) s += color_emb[v * 16 + e] * W1[(p * 32 + 16 + e) * 256 + h];
      CT[(id - 400) * 256 + h] = s;
    } else {
      int r = id - 800;
      if (r < 6) {
        float s = 0.f;
#pragma unroll
        for (int e = 0; e < 16; ++e) s += action_emb[r * 16 + e] * W1[(816 + e) * 256 + h];
        AT[r * 256 + h] = s;
      } else if (r < 10) {
        int d = r - 6;
        float s = 0.f;
#pragma unroll
        for (int e = 0; e < 16; ++e) s += Wdir[d * 16 + e] * W1[(800 + e) * 256 + h];
        WD1[d * 256 + h] = s;
      } else if (r == 10) {
        float s = b1[h];
#pragma unroll
        for (int e = 0; e < 16; ++e) s += bdir[e] * W1[(800 + e) * 256 + h];
        B1T[h] = s;
      } else if (r == 11) {
        WRW[h] = W1[832 * 256 + h];
      } else if (r == 12) {
        WDN[h] = W1[833 * 256 + h];
      }
    }
  } else if (id < 944) {
    // ---- W2T = [Wx;Wh]^T bf16, pc-permuted, LDS-XOR-preswizzled ----
    int wb = id - 816;
#pragma unroll
    for (int kk = 0; kk < 4; ++kk) {
      int k = wb * 4 + kk;
      const float* row = (k < 256) ? (Wx + (size_t)k * 1024)
                                   : (Wh + (size_t)(k - 256) * 1024);
      float4 v4 = *(const float4*)(row + h * 4);
      float vv[4] = {v4.x, v4.y, v4.z, v4.w};
#pragma unroll
      for (int e = 0; e < 4; ++e) {
        int n = h * 4 + e;
        int gate = n >> 8, rem = n & 255;
        int q = rem >> 5, jl = rem & 31;
        int pcl = (jl >> 2) * 16 + (jl & 3) * 4 + gate;
        unsigned byteoff = ((unsigned)(pcl << 10) + (unsigned)(k << 1)) ^
                           (((unsigned)(pcl & 7)) << 4);
        __hip_bfloat16 bv16 = __float2bfloat16(vv[e]);
        *(u16*)(ws + WS_W2T + (size_t)q * 131072u + byteoff) = *(u16*)&bv16;
      }
    }
  } else if (id < 3248) {
    // ---- misc init ----
    int mb = id - 944;
    int i = mb * 256 + h;
    if (mb < 512) {                       // h0 -> ring slot 0, tag 0
      unsigned* hdb = (unsigned*)(ws + WS_HDB);
      __hip_bfloat16 hb = __float2bfloat16(h0[i]);
      hdb[i] = (unsigned)*(u16*)&hb;      // tag = 0 in high bits
    } else if (mb < 2048) {               // logits = bpi
      int j = i - 131072;
      out[j] = bpi[j % 6];
    } else {                              // values = bv
      int j = i - 524288;
      out[393216 + j] = bv[0];
    }
  } else {
    // ---- hdb ring slot 1 -> 0xAA stale-tag fill (replaces hipMemsetAsync) --
    int mb2 = id - 3248;                  // 0..511
    unsigned* hdb = (unsigned*)(ws + WS_HDB);
    hdb[131072 + mb2 * 256 + h] = 0xAAAAAAAAu;
  }
}

// ---------------- x = relu(enc @ W1 + b1)  via tables -----------------------
__global__ __launch_bounds__(512, 1) void k_x(
    const int* obs_img, const float* obs_dir, const int* prev_action,
    const float* prev_reward, const float* done, char* ws) {
  __shared__ float TtL[12800];   // [25*16][32]
  __shared__ float CtL[12800];
  __shared__ float AtL[192];
  __shared__ float WdL[128];
  __shared__ u8 pkT[6400];       // [256 tb][25]
  __shared__ u8 pkC[6400];
  __shared__ u8 actL[256];
  __shared__ float rewL[256];
  __shared__ float dnL[256];
  __shared__ float dirL[1024];

  const float* TT  = (const float*)(ws + WS_TT);
  const float* CT  = (const float*)(ws + WS_CT);
  const float* AT  = (const float*)(ws + WS_AT);
  const float* WD1 = (const float*)(ws + WS_WD1);
  const float* B1T = (const float*)(ws + WS_B1T);
  const float* WRW = (const float*)(ws + WS_WRW);
  const float* WDN = (const float*)(ws + WS_WDN);
  __hip_bfloat16* xout = (__hip_bfloat16*)(ws + WS_X);

  int bid = blockIdx.x;          // 512 blocks
  int slice = bid & 7, grp = bid >> 3;   // 64 groups x 1024 tb
  int h0 = slice * 32;
  int tid = threadIdx.x;
  int sub = tid >> 5, hh = tid & 31;

  for (int e = tid; e < 12800; e += 512) {
    int pv = e >> 5, k = e & 31;
    TtL[e] = TT[pv * 256 + h0 + k];
    CtL[e] = CT[pv * 256 + h0 + k];
  }
  for (int e = tid; e < 192; e += 512) AtL[e] = AT[(e >> 5) * 256 + h0 + (e & 31)];
  for (int e = tid; e < 128; e += 512) WdL[e] = WD1[(e >> 5) * 256 + h0 + (e & 31)];
  float b1r = B1T[h0 + hh], wrr = WRW[h0 + hh], wdr = WDN[h0 + hh];

  for (int cg = 0; cg < 4; ++cg) {
    int tb0 = grp * 1024 + cg * 256;
    __syncthreads();
    for (int e = tid; e < 6400; e += 512) {
      int tbl = e / 25, p = e - tbl * 25;
      int base = ((tb0 + tbl) * 25 + p) * 2;
      pkT[e] = (u8)obs_img[base];
      pkC[e] = (u8)obs_img[base + 1];
    }
    for (int e = tid; e < 256; e += 512) {
      actL[e] = (u8)prev_action[tb0 + e];
      rewL[e] = prev_reward[tb0 + e];
      dnL[e]  = done[tb0 + e];
    }
    for (int e = tid; e < 1024; e += 512) dirL[e] = obs_dir[(size_t)tb0 * 4 + e];
    __syncthreads();

    for (int pass = 0; pass < 16; ++pass) {
      int tbl = pass * 16 + sub;
      float s0 = b1r, s1 = 0.f;
#pragma unroll
      for (int p = 0; p < 25; ++p) {
        int tv = pkT[tbl * 25 + p];
        int cv = pkC[tbl * 25 + p];
        s0 += TtL[(p * 16 + tv) * 32 + hh];
        s1 += CtL[(p * 16 + cv) * 32 + hh];
      }
      s0 += AtL[(int)actL[tbl] * 32 + hh];
      float d0 = dirL[tbl * 4 + 0], d1 = dirL[tbl * 4 + 1];
      float d2 = dirL[tbl * 4 + 2], d3 = dirL[tbl * 4 + 3];
      s1 += d0 * WdL[hh] + d1 * WdL[32 + hh] + d2 * WdL[64 + hh] + d3 * WdL[96 + hh];
      s0 += rewL[tbl] * wrr + dnL[tbl] * wdr;
      float xv = fmaxf(s0 + s1, 0.f);
      xout[(size_t)(tb0 + tbl) * 256 + h0 + hh] = __float2bfloat16(xv);
    }
  }
}

// ---------------- persistent fused LSTM (r10: early publish, split vmcnt) ---
__global__ __launch_bounds__(256, 1) void k_lstm(
    const float* c0, const float* bh, const float* Wpi, const float* Wv,
    float* out, char* ws) {
  __shared__ u16 W2T[65536];            // 128KB: [128 pc][512 k], XOR-swizzled
  __shared__ float WpiL[32][8];         // [j-local][a]; a=6 is Wv
  __shared__ float part[2][4][16][8];   // logits partials, dbuf by t&1
  __shared__ unsigned hstage[2][16 * 36]; // tagged h staging [slot][b][36-pad]

  const u16* xbf = (const u16*)(ws + WS_X);
  unsigned* hdb = (unsigned*)(ws + WS_HDB);  // tagged dwords [2][512 b][256 j]
  const u16* w2src = (const u16*)(ws + WS_W2T);

  const int tid = threadIdx.x;
  const int bid = blockIdx.x;
  const int c = bid & 31;             // cluster (batch slice)
  const int q = bid >> 5;             // hidden chunk (j in [q*32, q*32+32))
  const int b0 = c * 16;
  const int lane = tid & 63, wv = tid >> 6;
  const int G = lane >> 4, bl = lane & 15;

  {  // stage W2T slice (once)
    const s8v* src = (const s8v*)(w2src + (size_t)q * 65536);
    s8v* dst = (s8v*)W2T;
    for (int i = tid; i < 8192; i += 256) dst[i] = src[i];
  }
  {
    int jl = tid >> 3, a = tid & 7;
    int j = q * 32 + jl;
    WpiL[jl][a] = (a < 6) ? Wpi[j * 6 + a] : ((a == 6) ? Wv[j] : 0.f);
  }
  __syncthreads();

  const int jt0 = wv * 2, jt1 = wv * 2 + 1;
  const int jl0 = jt0 * 4 + G, jl1 = jt1 * 4 + G;
  const int myhj0 = q * 32 + jl0, myhj1 = q * 32 + jl1;
  const unsigned swz = ((unsigned)(bl & 7)) << 4;
  const unsigned ab0 = ((unsigned)(jt0 * 16 + bl)) << 10;
  const unsigned ab1 = ((unsigned)(jt1 * 16 + bl)) << 10;

  float bh0r[4], bh1r[4];
#pragma unroll
  for (int r = 0; r < 4; ++r) {
    bh0r[r] = bh[r * 256 + myhj0];
    bh1r[r] = bh[r * 256 + myhj1];
  }
  float cst0 = c0[(size_t)(b0 + bl) * 256 + myhj0];
  float cst1 = c0[(size_t)(b0 + bl) * 256 + myhj1];

  float* out_logits = out;
  float* out_values = out + 393216;
  float* out_cf = out + 458752;
  float* out_hf = out + 589824;

  for (int t = 0; t < 128; ++t) {
    // ---- 1) issue x-frag loads, then poll loads, all inline asm
    s8v xf[8];
    const u16* xr = xbf + ((size_t)t * 512 + (b0 + bl)) * 256 + 8 * G;
#pragma unroll
    for (int ks = 0; ks < 8; ++ks)
      asm volatile("global_load_dwordx4 %0, %1, off"
                   : "=v"(xf[ks]) : "v"(xr + ks * 32));

    U4 qv[16];
    const unsigned* hp = hdb + (size_t)(t & 1) * 131072u +
                         (size_t)(b0 + bl) * 256u + (unsigned)(G * 8);
#pragma unroll
    for (int i = 0; i < 16; ++i) {
      if ((i >> 1) != q || t == 0)   // own chunk comes from LDS when t>0
        asm volatile("global_load_dwordx4 %0, %1, off sc0 sc1"
                     : "=v"(qv[i].v4) : "v"(hp + (i >> 1) * 32 + (i & 1) * 4));
    }
    // x loads (issued first, in-order counter) complete at vmcnt(14);
    // poll loads stay in flight under the x-MFMAs.
    asm volatile("s_waitcnt vmcnt(14)" ::: "memory");
    __builtin_amdgcn_sched_barrier(0);

    // ---- 2) x-MFMAs overlap the first poll flight
    f4v acc0 = {0.f, 0.f, 0.f, 0.f};
    f4v acc1 = {0.f, 0.f, 0.f, 0.f};
#pragma unroll
    for (int ks = 0; ks < 8; ++ks) {
      unsigned k2 = (unsigned)(ks * 64 + G * 16);
      s8v a0 = *(const s8v*)((const char*)W2T + ((ab0 + k2) ^ swz));
      s8v a1 = *(const s8v*)((const char*)W2T + ((ab1 + k2) ^ swz));
      acc0 = __builtin_amdgcn_mfma_f32_16x16x32_bf16(a0, xf[ks], acc0, 0, 0, 0);
      acc1 = __builtin_amdgcn_mfma_f32_16x16x32_bf16(a1, xf[ks], acc1, 0, 0, 0);
    }
    asm volatile("s_waitcnt vmcnt(0)" ::: "memory");
    __builtin_amdgcn_sched_barrier(0);

    // ---- 3) tag check + re-poll (s_sleep backoff, as r8)
    const unsigned tq = (unsigned)t;
    bool ok = true;
#pragma unroll
    for (int i = 0; i < 16; ++i) {
      if ((i >> 1) == q && t != 0) continue;
#pragma unroll
      for (int c2 = 0; c2 < 4; ++c2) ok &= ((qv[i].u[c2] >> 16) == tq);
    }
    while (!ok) {
      __builtin_amdgcn_s_sleep(2);
#pragma unroll
      for (int i = 0; i < 16; ++i) {
        if ((i >> 1) != q || t == 0)
          asm volatile("global_load_dwordx4 %0, %1, off sc0 sc1"
                       : "=v"(qv[i].v4) : "v"(hp + (i >> 1) * 32 + (i & 1) * 4));
      }
      asm volatile("s_waitcnt vmcnt(0)" ::: "memory");
      __builtin_amdgcn_sched_barrier(0);
      ok = true;
#pragma unroll
      for (int i = 0; i < 16; ++i) {
        if ((i >> 1) == q && t != 0) continue;
#pragma unroll
        for (int c2 = 0; c2 < 4; ++c2) ok &= ((qv[i].u[c2] >> 16) == tq);
      }
    }

    // ---- 4) h-MFMAs (own chunk from hstage[t&1])
#pragma unroll
    for (int ks = 0; ks < 8; ++ks) {
      union { s8v v; unsigned u[4]; } bu;
      if (ks == q && t != 0) {
        const unsigned* hs = &hstage[t & 1][bl * 36 + G * 8];
        bu.u[0] = (hs[0] & 0xffffu) | (hs[1] << 16);
        bu.u[1] = (hs[2] & 0xffffu) | (hs[3] << 16);
        bu.u[2] = (hs[4] & 0xffffu) | (hs[5] << 16);
        bu.u[3] = (hs[6] & 0xffffu) | (hs[7] << 16);
      } else {
        const unsigned* pa = qv[ks * 2].u;
        const unsigned* pb = qv[ks * 2 + 1].u;
        bu.u[0] = (pa[0] & 0xffffu) | (pa[1] << 16);
        bu.u[1] = (pa[2] & 0xffffu) | (pa[3] << 16);
        bu.u[2] = (pb[0] & 0xffffu) | (pb[1] << 16);
        bu.u[3] = (pb[2] & 0xffffu) | (pb[3] << 16);
      }
      unsigned k2 = (unsigned)((ks + 8) * 64 + G * 16);
      s8v a0 = *(const s8v*)((const char*)W2T + ((ab0 + k2) ^ swz));
      s8v a1 = *(const s8v*)((const char*)W2T + ((ab1 + k2) ^ swz));
      acc0 = __builtin_amdgcn_mfma_f32_16x16x32_bf16(a0, bu.v, acc0, 0, 0, 0);
      acc1 = __builtin_amdgcn_mfma_f32_16x16x32_bf16(a1, bu.v, acc1, 0, 0, 0);
    }

    // ---- 5) gates (lane-local: acc[r] = gate r of (b0+bl, myhj))
    float zi0 = acc0[0] + bh0r[0], zf0 = acc0[1] + bh0r[1];
    float zg0 = acc0[2] + bh0r[2], zo0 = acc0[3] + bh0r[3];
    float cn0 = sigm_(zf0) * cst0 + sigm_(zi0) * tanh_(zg0);
    float hn0 = sigm_(zo0) * tanh_(cn0);
    cst0 = cn0;
    float zi1 = acc1[0] + bh1r[0], zf1 = acc1[1] + bh1r[1];
    float zg1 = acc1[2] + bh1r[2], zo1 = acc1[3] + bh1r[3];
    float cn1 = sigm_(zf1) * cst1 + sigm_(zi1) * tanh_(zg1);
    float hn1 = sigm_(zo1) * tanh_(cn1);
    cst1 = cn1;

    // ---- 6) early publish: per-lane tagged sc01 stores straight from regs
    const int wslot = (t + 1) & 1, pt = t & 1;
    if (t < 127) {
      __hip_bfloat16 hb0 = __float2bfloat16(hn0);
      __hip_bfloat16 hb1 = __float2bfloat16(hn1);
      unsigned d0 = ((unsigned)(t + 1) << 16) | (unsigned)*(u16*)&hb0;
      unsigned d1 = ((unsigned)(t + 1) << 16) | (unsigned)*(u16*)&hb1;
      unsigned* hw = hdb + (size_t)wslot * 131072u + (size_t)(b0 + bl) * 256u;
      asm volatile("global_store_dword %0, %1, off sc0 sc1"
                   :: "v"(hw + myhj0), "v"(d0) : "memory");
      asm volatile("global_store_dword %0, %1, off sc0 sc1"
                   :: "v"(hw + myhj1), "v"(d1) : "memory");
      // own-chunk fast path for next step
      hstage[wslot][bl * 36 + jl0] = d0;
      hstage[wslot][bl * 36 + jl1] = d1;
    } else {
      size_t o = (size_t)(b0 + bl) * 256;
      out_cf[o + myhj0] = cst0;
      out_cf[o + myhj1] = cst1;
      out_hf[o + myhj0] = hn0;
      out_hf[o + myhj1] = hn1;
    }

    // ---- 7) logits/value partials (overlaps publish flight)
    float pl[7];
#pragma unroll
    for (int a = 0; a < 7; ++a) {
      float s = hn0 * WpiL[jl0][a] + hn1 * WpiL[jl1][a];
      s += __shfl_xor(s, 16, 64);
      s += __shfl_xor(s, 32, 64);
      pl[a] = s;
    }
    if (lane < 16) {
#pragma unroll
      for (int a = 0; a < 7; ++a) part[pt][wv][bl][a] = pl[a];
    }

    __syncthreads();

    // ---- 8) logits adds (waves 2-3 only; publish already issued)
    if (tid >= 128) {
      int i2 = tid - 128, b_ = i2 >> 3, a_ = i2 & 7;
      if (a_ < 7) {
        float s = part[pt][0][b_][a_] + part[pt][1][b_][a_] +
                  part[pt][2][b_][a_] + part[pt][3][b_][a_];
        if (a_ < 6)
          atomicAdd(out_logits + ((size_t)t * 512 + b0 + b_) * 6 + a_, s);
        else
          atomicAdd(out_values + (size_t)t * 512 + b0 + b_, s);
      }
    }
  }
}

extern "C" void kernel_launch(void* const* d_in, const int* in_sizes, int n_in,
                              void* d_out, int out_size, void* d_ws, size_t ws_size,
                              hipStream_t stream) {
  const int*   obs_img     = (const int*)d_in[0];
  const float* obs_dir     = (const float*)d_in[1];
  const int*   prev_action = (const int*)d_in[2];
  const float* prev_reward = (const float*)d_in[3];
  const float* done        = (const float*)d_in[4];
  const float* c0          = (const float*)d_in[5];
  const float* h0          = (const float*)d_in[6];
  const float* tile_emb    = (const float*)d_in[7];
  const float* color_emb   = (const float*)d_in[8];
  const float* action_emb  = (const float*)d_in[9];
  const float* Wdir        = (const float*)d_in[10];
  const float* bdir        = (const float*)d_in[11];
  const float* W1          = (const float*)d_in[12];
  const float* b1          = (const float*)d_in[13];
  const float* Wx          = (const float*)d_in[14];
  const float* Wh          = (const float*)d_in[15];
  const float* bh          = (const float*)d_in[16];
  const float* Wpi         = (const float*)d_in[17];
  const float* bpi         = (const float*)d_in[18];
  const float* Wv          = (const float*)d_in[19];
  const float* bv          = (const float*)d_in[20];
  (void)in_sizes; (void)n_in; (void)out_size; (void)ws_size;

  char* ws = (char*)d_ws;
  float* out = (float*)d_out;

  // hdb stale-tag fill now done inside k_prep (slot 0 by h0-init, slot 1 by
  // the 0xAA blocks) -- no SDMA memset on the critical path.
  k_prep<<<3760, 256, 0, stream>>>(tile_emb, color_emb, action_emb, Wdir, bdir,
                                   W1, b1, Wx, Wh, h0, bpi, bv, out, ws);
  k_x<<<512, 512, 0, stream>>>(obs_img, obs_dir, prev_action, prev_reward, done, ws);
  k_lstm<<<256, 256, 0, stream>>>(c0, bh, Wpi, Wv, out, ws);
}